// Round 9
// baseline (298.651 us; speedup 1.0000x reference)
//
#include <hip/hip_runtime.h>
#include <hip/hip_bf16.h>

#define BB 2
#define SS 2048
#define DD 1024
#define HH 16
#define DKK 64
// M = BB*SS = 4096, N = K = DD = 1024
// Q pre-scale: (1/sqrt(64)) * log2(e), so scores are in log2 domain
#define QSCALE 0.180336880f
// fixed softmax shift (log2 domain). Scores s' = s*log2e, |s| <~ 2.5 => s' in ~[-4,4].
// p = 2^(s'-23): no overflow, no underflow; shift cancels in softmax exactly.
#define M2 23.0f
// masked score (log2 domain): weight 2^(-43-23)=2^-66 ~ 1e-20 (== -1e9 semantics;
// fully-masked row -> all-equal -> uniform, matching reference)
#define MASKED2 -43.0f

typedef __hip_bfloat16 bf16;
typedef unsigned short u16;
using frag_ab = __attribute__((ext_vector_type(8))) short;  // 8 bf16 (4 VGPRs)
using frag_cd = __attribute__((ext_vector_type(4))) float;  // 4 fp32

__device__ inline u16 f2bf(float f) {
    bf16 h = __float2bfloat16(f);
    return *reinterpret_cast<u16*>(&h);
}

// async global->LDS, 16B per lane (lds dest = wave-uniform base + lane*16)
__device__ inline void gld16(const void* g, void* l) {
    __builtin_amdgcn_global_load_lds((const __attribute__((address_space(1))) void*)g,
                                     (__attribute__((address_space(3))) void*)l,
                                     16, 0, 0);
}

// ---------------- prep: fp32->bf16 converts + mask tile flags ----------------
__global__ __launch_bounds__(256) void prep(
    const float* __restrict__ q, const float* __restrict__ k, const float* __restrict__ v,
    const float* __restrict__ Wq, const float* __restrict__ Wk,
    const float* __restrict__ Wv, const float* __restrict__ Wo,
    u16* __restrict__ qb, u16* __restrict__ kb, u16* __restrict__ vb,
    u16* __restrict__ Wqb, u16* __restrict__ Wkb, u16* __restrict__ Wvb, u16* __restrict__ Wob,
    const int* __restrict__ mask, int* __restrict__ flags) {
    int bid = blockIdx.x;
    int t = threadIdx.x;
    if (bid < 8192) {
        const float* src;
        u16* dst;
        int local;
        if (bid < 6144) {
            int ts = bid >> 11;
            local = bid & 2047;
            src = ts == 0 ? q : (ts == 1 ? k : v);
            dst = ts == 0 ? qb : (ts == 1 ? kb : vb);
        } else {
            int wsel = (bid - 6144) >> 9;
            local = (bid - 6144) & 511;
            src = wsel == 0 ? Wq : (wsel == 1 ? Wk : (wsel == 2 ? Wv : Wo));
            dst = wsel == 0 ? Wqb : (wsel == 1 ? Wkb : (wsel == 2 ? Wvb : Wob));
        }
        size_t base = (size_t)local * 2048 + t * 8;
        float4 a = *(const float4*)&src[base];
        float4 b = *(const float4*)&src[base + 4];
        ushort4 u0, u1;
        u0.x = f2bf(a.x); u0.y = f2bf(a.y); u0.z = f2bf(a.z); u0.w = f2bf(a.w);
        u1.x = f2bf(b.x); u1.y = f2bf(b.y); u1.z = f2bf(b.z); u1.w = f2bf(b.w);
        *(ushort4*)&dst[base] = u0;
        *(ushort4*)&dst[base + 4] = u1;
    } else {
        int tile = bid - 8192;
        int qt = tile >> 5, kt = tile & 31;
        __shared__ int f;
        if (t == 0) f = 0;
        __syncthreads();
        int qq = qt * 64 + (t >> 2);
        const int4* row = (const int4*)(mask + (size_t)qq * SS + kt * 64 + (t & 3) * 16);
        int anyz = 0;
#pragma unroll
        for (int i = 0; i < 4; ++i) {
            int4 m4 = row[i];
            anyz |= (m4.x == 0) | (m4.y == 0) | (m4.z == 0) | (m4.w == 0);
        }
        if (anyz) f = 1;
        __syncthreads();
        if (t == 0) flags[tile] = f;
    }
}

// ---------------- fused QKV GEMM (bf16 in, bf16 out) ----------------
__global__ __launch_bounds__(256) void qkv_gemm(
    const u16* __restrict__ Aq, const u16* __restrict__ Ak, const u16* __restrict__ Av,
    const u16* __restrict__ Wq, const u16* __restrict__ Wk, const u16* __restrict__ Wv,
    const float* __restrict__ bq, const float* __restrict__ bk, const float* __restrict__ bv,
    u16* __restrict__ Qo, u16* __restrict__ Ko, u16* __restrict__ Vo) {
    __shared__ u16 As[128 * 32];
    __shared__ u16 Bs[128 * 32];

    int z = blockIdx.z;
    const u16* A = z == 0 ? Aq : (z == 1 ? Ak : Av);
    const u16* W = z == 0 ? Wq : (z == 1 ? Wk : Wv);
    const float* bias = z == 0 ? bq : (z == 1 ? bk : bv);
    u16* out = z == 0 ? Qo : (z == 1 ? Ko : Vo);

    int t = threadIdx.x;
    int m0 = blockIdx.y * 128;
    int n0 = blockIdx.x * 128;
    int w = t >> 6, lane = t & 63;
    int quad = lane >> 4, l16 = lane & 15;
    int wm = w >> 1, wn = w & 1;

    const u16* Ab = A + (size_t)m0 * DD;
    const u16* Wb = W + (size_t)n0 * DD;

    frag_cd acc[4][4];
#pragma unroll
    for (int mt = 0; mt < 4; ++mt)
#pragma unroll
        for (int nt = 0; nt < 4; ++nt) acc[mt][nt] = frag_cd{0.f, 0.f, 0.f, 0.f};

    for (int k0 = 0; k0 < DD; k0 += 32) {
        if (k0) __syncthreads();
#pragma unroll
        for (int i = 0; i < 2; ++i) {
            int c = t + i * 256;
            int row = c >> 2, kc = (c & 3) * 8;
            gld16(Ab + (size_t)row * DD + k0 + kc, &As[c * 8]);
            gld16(Wb + (size_t)row * DD + k0 + kc, &Bs[c * 8]);
        }
        __syncthreads();

        frag_ab af[4], bfr[4];
#pragma unroll
        for (int mt = 0; mt < 4; ++mt)
            af[mt] = *(const frag_ab*)&As[(wm * 64 + mt * 16 + l16) * 32 + quad * 8];
#pragma unroll
        for (int nt = 0; nt < 4; ++nt)
            bfr[nt] = *(const frag_ab*)&Bs[(wn * 64 + nt * 16 + l16) * 32 + quad * 8];
#pragma unroll
        for (int mt = 0; mt < 4; ++mt)
#pragma unroll
            for (int nt = 0; nt < 4; ++nt)
                acc[mt][nt] = __builtin_amdgcn_mfma_f32_16x16x32_bf16(
                    af[mt], bfr[nt], acc[mt][nt], 0, 0, 0);
    }

    float scale = z == 0 ? QSCALE : 1.0f;
#pragma unroll
    for (int nt = 0; nt < 4; ++nt) {
        int n = n0 + wn * 64 + nt * 16 + l16;
        float bv_ = bias[n];
        int h_ = n >> 6, d_ = n & 63;
#pragma unroll
        for (int mt = 0; mt < 4; ++mt) {
            int mb = m0 + wm * 64 + mt * 16 + quad * 4;
            int b_ = mb >> 11, s_ = mb & 2047;
            if (z == 2) {
                ushort4 u;
                u.x = f2bf(acc[mt][nt][0] + bv_);
                u.y = f2bf(acc[mt][nt][1] + bv_);
                u.z = f2bf(acc[mt][nt][2] + bv_);
                u.w = f2bf(acc[mt][nt][3] + bv_);
                *(ushort4*)&out[((size_t)(b_ * HH + h_) * DKK + d_) * SS + s_] = u;
            } else {
#pragma unroll
                for (int r = 0; r < 4; ++r)
                    out[((size_t)(b_ * HH + h_) * SS + s_ + r) * DKK + d_] =
                        f2bf((acc[mt][nt][r] + bv_) * scale);
            }
        }
    }
}

// ---------------- output GEMM: fp32 out = Cw(bf16) @ Wo^T + bo ----------------
__global__ __launch_bounds__(256) void out_gemm(const u16* __restrict__ A,
                                                const u16* __restrict__ W,
                                                const float* __restrict__ bias,
                                                float* __restrict__ out) {
    __shared__ u16 As[128 * 32];
    __shared__ u16 Bs[128 * 32];

    int t = threadIdx.x;
    int m0 = blockIdx.y * 128;
    int n0 = blockIdx.x * 128;
    int w = t >> 6, lane = t & 63;
    int quad = lane >> 4, l16 = lane & 15;
    int wm = w >> 1, wn = w & 1;

    const u16* Ab = A + (size_t)m0 * DD;
    const u16* Wb = W + (size_t)n0 * DD;

    frag_cd acc[4][4];
#pragma unroll
    for (int mt = 0; mt < 4; ++mt)
#pragma unroll
        for (int nt = 0; nt < 4; ++nt) acc[mt][nt] = frag_cd{0.f, 0.f, 0.f, 0.f};

    for (int k0 = 0; k0 < DD; k0 += 32) {
        if (k0) __syncthreads();
#pragma unroll
        for (int i = 0; i < 2; ++i) {
            int c = t + i * 256;
            int row = c >> 2, kc = (c & 3) * 8;
            gld16(Ab + (size_t)row * DD + k0 + kc, &As[c * 8]);
            gld16(Wb + (size_t)row * DD + k0 + kc, &Bs[c * 8]);
        }
        __syncthreads();

        frag_ab af[4], bfr[4];
#pragma unroll
        for (int mt = 0; mt < 4; ++mt)
            af[mt] = *(const frag_ab*)&As[(wm * 64 + mt * 16 + l16) * 32 + quad * 8];
#pragma unroll
        for (int nt = 0; nt < 4; ++nt)
            bfr[nt] = *(const frag_ab*)&Bs[(wn * 64 + nt * 16 + l16) * 32 + quad * 8];
#pragma unroll
        for (int mt = 0; mt < 4; ++mt)
#pragma unroll
            for (int nt = 0; nt < 4; ++nt)
                acc[mt][nt] = __builtin_amdgcn_mfma_f32_16x16x32_bf16(
                    af[mt], bfr[nt], acc[mt][nt], 0, 0, 0);
    }

#pragma unroll
    for (int nt = 0; nt < 4; ++nt) {
        int n = n0 + wn * 64 + nt * 16 + l16;
        float bv_ = bias[n];
#pragma unroll
        for (int mt = 0; mt < 4; ++mt) {
            int mb = m0 + wm * 64 + mt * 16 + quad * 4;
#pragma unroll
            for (int r = 0; r < 4; ++r)
                out[(size_t)(mb + r) * DD + n] = acc[mt][nt][r] + bv_;
        }
    }
}

// ---------------- flash attention: 32-q blocks, fixed-shift softmax ----------------
// Grid: B*H*(S/32) = 2048 blocks, 256 threads (4 waves).
// Wave w: q-sub (w>>1) (16 q's), key-half (w&1) (32 of each 64-key tile).
// Fixed shift => waves fully independent until a single epilogue reduction.
__global__ __launch_bounds__(256) void attn_mfma(const u16* __restrict__ Qb,
                                                 const u16* __restrict__ Kb,
                                                 const u16* __restrict__ Vb,
                                                 const int* __restrict__ mask,
                                                 const int* __restrict__ flags,
                                                 u16* __restrict__ C) {
    __shared__ u16 Ks[64 * 64];       // [key][d]   (reused as fp32 O buffer at end)
    __shared__ u16 Vt[64 * 64];       // [d][key]   (reused as fp32 l buffer at end)
    __shared__ u16 Pw[4][16 * 40];    // per-wave P^T [q][32 keys], padded stride

    int blk = blockIdx.x;
    int qt = blk & 63;           // 32-q tile
    int bh = blk >> 6;
    int h = bh & 15;
    int b = bh >> 4;
    int q0 = qt * 32;

    const u16* Kg = Kb + (size_t)bh * SS * DKK;
    const u16* Vg = Vb + (size_t)bh * DKK * SS;
    const int* flg = flags + (q0 >> 6) * 32;

    int t = threadIdx.x;
    int w = t >> 6;
    int lane = t & 63;
    int quad = lane >> 4;
    int l16 = lane & 15;
    int qsub = w >> 1;           // 0,1
    int kh = w & 1;              // key half 0,1

    // ---- Q B-frags direct from global (loop-invariant) ----
    frag_ab bq0, bq1;
    {
        const u16* Qr = Qb + ((size_t)bh * SS + q0 + qsub * 16 + l16) * DKK;
        bq0 = *(const frag_ab*)&Qr[quad * 8];
        bq1 = *(const frag_ab*)&Qr[32 + quad * 8];
    }

    frag_cd o[4];
#pragma unroll
    for (int dt = 0; dt < 4; ++dt) o[dt] = frag_cd{0.f, 0.f, 0.f, 0.f};
    float l_run = 0.f;

    // staging geometry (all 256 threads stage the full 64-key K and V tiles)
    int vd = t >> 2;
    int vc = (t & 3) * 16;

    int4 kr0, kr1, vr0, vr1;
    {
        const int4* Kt = (const int4*)Kg;
        kr0 = Kt[2 * t]; kr1 = Kt[2 * t + 1];
        const int4* Vr = (const int4*)(Vg + (size_t)vd * SS + vc);
        vr0 = Vr[0]; vr1 = Vr[1];
    }

    for (int kt = 0; kt < 32; ++kt) {
        if (kt) __syncthreads();  // (A) prior tile's frag reads complete
        ((int4*)Ks)[2 * t] = kr0;
        ((int4*)Ks)[2 * t + 1] = kr1;
        *(int4*)&Vt[vd * 64 + vc] = vr0;
        *(int4*)&Vt[vd * 64 + vc + 8] = vr1;
        if (kt < 31) {
            const int4* Kt = (const int4*)(Kg + (size_t)(kt + 1) * 4096);
            kr0 = Kt[2 * t]; kr1 = Kt[2 * t + 1];
            const int4* Vr = (const int4*)(Vg + (size_t)vd * SS + (kt + 1) * 64 + vc);
            vr0 = Vr[0]; vr1 = Vr[1];
        }
        int anyzero = flg[kt];
        __syncthreads();  // (B) staged tile visible

        // ---- S^T for this wave: 2 key-subtiles (its 32 keys) x 16 q ----
        float s[2][4];
#pragma unroll
        for (int nt = 0; nt < 2; ++nt) {
            int kr = kh * 32 + nt * 16 + l16;
            frag_ab ak0 = *(const frag_ab*)&Ks[kr * 64 + quad * 8];
            frag_ab ak1 = *(const frag_ab*)&Ks[kr * 64 + 32 + quad * 8];
            frag_cd sf = frag_cd{0.f, 0.f, 0.f, 0.f};
            sf = __builtin_amdgcn_mfma_f32_16x16x32_bf16(ak0, bq0, sf, 0, 0, 0);
            sf = __builtin_amdgcn_mfma_f32_16x16x32_bf16(ak1, bq1, sf, 0, 0, 0);
#pragma unroll
            for (int r = 0; r < 4; ++r) s[nt][r] = sf[r];
        }

        if (anyzero) {
            int qg = q0 + qsub * 16 + l16;
#pragma unroll
            for (int nt = 0; nt < 2; ++nt)
#pragma unroll
                for (int r = 0; r < 4; ++r) {
                    int kg = kt * 64 + kh * 32 + nt * 16 + quad * 4 + r;
                    if (mask[(size_t)qg * SS + kg] == 0) s[nt][r] = MASKED2;
                }
        }

        // ---- fixed-shift softmax numerator: p = 2^(s - M2), per-lane l accum ----
        float p[2][4];
#pragma unroll
        for (int nt = 0; nt < 2; ++nt)
#pragma unroll
            for (int r = 0; r < 4; ++r) {
                p[nt][r] = __builtin_amdgcn_exp2f(s[nt][r] - M2);
                l_run += p[nt][r];
            }

        // ---- P^T store: Pw[q=l16][local key] ----
#pragma unroll
        for (int nt = 0; nt < 2; ++nt) {
            ushort4 up;
            up.x = f2bf(p[nt][0]); up.y = f2bf(p[nt][1]);
            up.z = f2bf(p[nt][2]); up.w = f2bf(p[nt][3]);
            *(ushort4*)&Pw[w][l16 * 40 + nt * 16 + quad * 4] = up;
        }
        frag_ab bp = *(const frag_ab*)&Pw[w][l16 * 40 + quad * 8];

        // ---- O^T += V^T(this key-half) · P^T ----
#pragma unroll
        for (int dt = 0; dt < 4; ++dt) {
            int dr = dt * 16 + l16;
            frag_ab av = *(const frag_ab*)&Vt[dr * 64 + kh * 32 + quad * 8];
            o[dt] = __builtin_amdgcn_mfma_f32_16x16x32_bf16(av, bp, o[dt], 0, 0, 0);
        }
    }

    // ---- epilogue: combine the two key-half waves per q-sub ----
    __syncthreads();  // last iter's Ks/Vt reads done; safe to reuse as fp32 bufs
    float* Ob = (float*)Ks;   // [2][16 q][64 d] fp32 = 8 KB
    float* Lb = (float*)Vt;   // [2][16] fp32

    l_run += __shfl_xor(l_run, 16);
    l_run += __shfl_xor(l_run, 32);

    if (kh == 1) {
#pragma unroll
        for (int dt = 0; dt < 4; ++dt) {
            float4 val;
            val.x = o[dt][0]; val.y = o[dt][1]; val.z = o[dt][2]; val.w = o[dt][3];
            *(float4*)&Ob[qsub * 1024 + l16 * 64 + dt * 16 + quad * 4] = val;
        }
        if (quad == 0) Lb[qsub * 16 + l16] = l_run;
    }
    __syncthreads();
    if (kh == 0) {
        float inv = 1.f / (l_run + Lb[qsub * 16 + l16]);
        int qg = q0 + qsub * 16 + l16;
        u16* Crow = C + ((size_t)b * SS + qg) * DD + h * 64;
#pragma unroll
        for (int dt = 0; dt < 4; ++dt) {
            float4 other = *(const float4*)&Ob[qsub * 1024 + l16 * 64 + dt * 16 + quad * 4];
            ushort4 u;
            u.x = f2bf((o[dt][0] + other.x) * inv);
            u.y = f2bf((o[dt][1] + other.y) * inv);
            u.z = f2bf((o[dt][2] + other.z) * inv);
            u.w = f2bf((o[dt][3] + other.w) * inv);
            *(ushort4*)&Crow[dt * 16 + quad * 4] = u;
        }
    }
}

extern "C" void kernel_launch(void* const* d_in, const int* in_sizes, int n_in,
                              void* d_out, int out_size, void* d_ws, size_t ws_size,
                              hipStream_t stream) {
    const float* q = (const float*)d_in[0];
    const float* k = (const float*)d_in[1];
    const float* v = (const float*)d_in[2];
    const int* mask = (const int*)d_in[3];
    const float* Wq = (const float*)d_in[4];
    const float* bq = (const float*)d_in[5];
    const float* Wk = (const float*)d_in[6];
    const float* bk = (const float*)d_in[7];
    const float* Wv = (const float*)d_in[8];
    const float* bv = (const float*)d_in[9];
    const float* Wo = (const float*)d_in[10];
    const float* bo = (const float*)d_in[11];
    float* out = (float*)d_out;

    const size_t MB = 1024u * 1024u;
    char* ws = (char*)d_ws;
    u16* qb = (u16*)(ws + 0 * MB);     // 8 MB (reused as Cw after qkv_gemm)
    u16* kb = (u16*)(ws + 8 * MB);
    u16* vb = (u16*)(ws + 16 * MB);
    u16* Wqb = (u16*)(ws + 24 * MB);
    u16* Wkb = (u16*)(ws + 26 * MB);
    u16* Wvb = (u16*)(ws + 28 * MB);
    u16* Wob = (u16*)(ws + 30 * MB);
    u16* Qb = (u16*)(ws + 32 * MB);
    u16* Kb = (u16*)(ws + 40 * MB);
    u16* Vb = (u16*)(ws + 48 * MB);
    int* flags = (int*)(ws + 56 * MB);
    u16* Cw = qb;

    prep<<<9216, 256, 0, stream>>>(q, k, v, Wq, Wk, Wv, Wo,
                                   qb, kb, vb, Wqb, Wkb, Wvb, Wob, mask, flags);

    dim3 grid(DD / 128, (BB * SS) / 128, 3);
    qkv_gemm<<<grid, 256, 0, stream>>>(qb, kb, vb, Wqb, Wkb, Wvb,
                                       bq, bk, bv, Qb, Kb, Vb);

    attn_mfma<<<BB * HH * (SS / 32), 256, 0, stream>>>(Qb, Kb, Vb, mask, flags, Cw);

    out_gemm<<<dim3(DD / 128, (BB * SS) / 128), 256, 0, stream>>>(Cw, Wob, bo, out);
}